// Round 5
// baseline (135.968 us; speedup 1.0000x reference)
//
#include <hip/hip_runtime.h>

#define NLAYERS 32
#define H 16
#define INDIM 124
#define NT 4   // batch tiles per wave

typedef __fp16 pk16x2 __attribute__((ext_vector_type(2)));   // cvt_pkrtz result
typedef _Float16 half4 __attribute__((ext_vector_type(4)));
typedef _Float16 half8 __attribute__((ext_vector_type(8)));
typedef float floatx4 __attribute__((ext_vector_type(4)));
typedef float floatx2 __attribute__((ext_vector_type(2)));
typedef int intx2 __attribute__((ext_vector_type(2)));
typedef int intx4 __attribute__((ext_vector_type(4)));

static __device__ __forceinline__ half4 mk_half4(pk16x2 a, pk16x2 b) {
    intx2 v;
    v.x = __builtin_bit_cast(int, a);
    v.y = __builtin_bit_cast(int, b);
    return __builtin_bit_cast(half4, v);
}
static __device__ __forceinline__ half8 mk_half8(pk16x2 a, pk16x2 b,
                                                 pk16x2 c, pk16x2 d) {
    intx4 v;
    v.x = __builtin_bit_cast(int, a);
    v.y = __builtin_bit_cast(int, b);
    v.z = __builtin_bit_cast(int, c);
    v.w = __builtin_bit_cast(int, d);
    return __builtin_bit_cast(half8, v);
}
static __device__ __forceinline__ half4 low_half(half8 v) {
    intx4 i = __builtin_bit_cast(intx4, v);
    intx2 r; r.x = i.x; r.y = i.y;
    return __builtin_bit_cast(half4, r);
}

// Split-f16 MFMA residual MLP.  hT lives in the MFMA D-fragment
// (m=quad*4+r, n=lane&15) == the next MFMA's B-fragment layout.
// Per residual layer: d = MFMA16(wh, hhi, bias) then one K=32 correction
// MFMA with A' = column-interleaved [WThi | WTlo] and B' = {hlo[0:4], hhi[0:4]}.
// leaky(x) = 0.6x + 0.4|x| -> two FMAs.  hlo = h - (h & 0xFFFFE000).
//
// This round vs round 4 (80.6 us kernel / 135 us bench): kernel body is
// VERBATIM round 4.  Launch geometry only: 1024 blocks x 512 threads
// (8 waves) instead of 2048 x 256.  Same 8192 waves, same 32 waves/CU
// (LDS 6144 -> 4 blocks/CU x 8 waves), HALF the workgroups.  Evidence from
// R0 (1024 blocks, bench-kernel gap ~15us) vs R3/R4 (2048 blocks, gap
// ~55us) points at per-workgroup launch/retire overhead outside the
// dispatch window; halving blocks should reclaim ~30us of bench time.
// launch_bounds(512, 4) = soft 128-VGPR cap; the HARD min-8 (64-VGPR) cap
// is the factor common to the two corrupted rounds (R1/R2) and absent from
// all passing rounds — not repeated here.
__global__ __launch_bounds__(512, 4) void fractal_kernel(
    const float* __restrict__ z, const float* __restrict__ c,
    const float* __restrict__ W1, const float* __restrict__ b1,
    const float* __restrict__ Ws, const float* __restrict__ bs,
    const float* __restrict__ Wf, const float* __restrict__ bf,
    float* __restrict__ out, int B)
{
    __shared__ half8 lds_w1hi[4 * 64];       // layer-1 hi A frags
    __shared__ floatx4 lds_bs[NLAYERS * 4];  // bias frags

    const int tid = threadIdx.x;
    const int lane = tid & 63;
    const int q = lane >> 4, col = lane & 15;

    // Stage W1^T hi fragments: A[m=col][k] = W1[k][col], k = t*32 + q*8 + j.
    if (tid < 256) {
        int t = tid >> 6, sl = tid & 63;
        int sq = sl >> 4, scol = sl & 15;
        half8 vh;
#pragma unroll
        for (int j = 0; j < 8; ++j) {
            int k = t * 32 + sq * 8 + j;
            float w = (k < INDIM) ? W1[k * H + scol] : 0.f;
            vh[j] = (_Float16)w;
        }
        lds_w1hi[tid] = vh;
    }
    for (int idx = tid; idx < NLAYERS * 4; idx += 512) {
        int l = idx >> 2, sq = idx & 3;
        floatx4 v;
#pragma unroll
        for (int j = 0; j < 4; ++j) v[j] = bs[l * H + sq * 4 + j];
        lds_bs[idx] = v;
    }

    // Layer-1 LO fragments live in registers (own lane's fragment only).
    half8 w1lo[4];
#pragma unroll
    for (int t = 0; t < 4; ++t) {
#pragma unroll
        for (int j = 0; j < 8; ++j) {
            int k = t * 32 + q * 8 + j;
            float w = (k < INDIM) ? W1[k * H + col] : 0.f;
            _Float16 hi = (_Float16)w;
            w1lo[t][j] = (_Float16)(w - (float)hi);
        }
    }
    __syncthreads();

    const int wave = (blockIdx.x * 512 + tid) >> 6;
    const int nwaves = (gridDim.x * 512) >> 6;   // 8192
    const int stride16 = nwaves * 16;            // batch stride between tiles

    constexpr float C_HI = 0.15915494309189535f;                        // fl(1/2pi)
    constexpr float C_LO = (float)(0.15915494309189535 - (double)C_HI); // residual

    const floatx2* z2 = (const floatx2*)z;
    const floatx2* c2 = (const floatx2*)c;
    const floatx4 bias1 = *(const floatx4*)(b1 + q * 4);
    const floatx4 wf4 = *(const floatx4*)(Wf + q * 4);
    const float bff = bf[0];

    const int n0 = wave * 16 + col;
    float h[NT][4];   // h[i][r]: master fp32 hidden state for tile i

    // ---- Layer 1: positional encoding + Dense(124->16) ----
    {
        float yh[4][4], yl[4][4];   // [tile][dim]
#pragma unroll
        for (int u = 0; u < 4; ++u) {
            const int n = n0 + u * stride16;
            floatx2 zz = z2[n], cc = c2[n];
            float xv[4] = {zz.x, zz.y, cc.x, cc.y};
            // two-float x/(2pi): x*2^i exact in fp32, so frac((yh+yl)*2^i)
            // gives an accurate phase for sin(x*2^i) without Payne-Hanek.
#pragma unroll
            for (int d = 0; d < 4; ++d) {
                yh[u][d] = xv[d] * C_HI;
                yl[u][d] = __builtin_fmaf(xv[d], C_HI, -yh[u][d]) + xv[d] * C_LO;
            }
            // raw features x_d needed later (t=0 cos slots, q==0); stash in h[].
#pragma unroll
            for (int r = 0; r < 4; ++r) h[u][r] = xv[r];
        }
        floatx4 acc[4] = {bias1, bias1, bias1, bias1};
#pragma unroll
        for (int t = 0; t < 4; ++t) {
            // features k = t*32 + q*8 + j: j<4 -> cos(2^(t*4+q-1) x_d),
            // j>=4 -> sin(2^(t*4+q) x_d), d=j&3; t=0,q=0,j<4 -> raw x.
            // k=124..127 hit zeroed A columns — values harmless.
            const float sc_cos = __builtin_ldexpf(1.0f, t * 4 + q - 1);
            const float sc_sin = __builtin_ldexpf(1.0f, t * 4 + q);
            half8 ah = lds_w1hi[t * 64 + lane];   // shared across 4 tiles
            half8 al = w1lo[t];
#pragma unroll
            for (int u = 0; u < 4; ++u) {
                float fv[8];
#pragma unroll
                for (int j = 0; j < 8; ++j) {
                    const int d = j & 3;
                    const bool is_cos = (j < 4);
                    const float sc = is_cos ? sc_cos : sc_sin;
                    float fr = __builtin_amdgcn_fractf(yh[u][d] * sc);
                    fr = __builtin_fmaf(yl[u][d], sc, fr);
                    if (is_cos) fr += 0.25f;             // cos = sin(+1/4 rev)
                    fv[j] = __builtin_amdgcn_sinf(fr);
                    if (t == 0 && is_cos && q == 0) fv[j] = h[u][j];
                }
                half8 bh = mk_half8(__builtin_amdgcn_cvt_pkrtz(fv[0], fv[1]),
                                    __builtin_amdgcn_cvt_pkrtz(fv[2], fv[3]),
                                    __builtin_amdgcn_cvt_pkrtz(fv[4], fv[5]),
                                    __builtin_amdgcn_cvt_pkrtz(fv[6], fv[7]));
                acc[u] = __builtin_amdgcn_mfma_f32_16x16x32_f16(ah, bh, acc[u], 0, 0, 0);
                acc[u] = __builtin_amdgcn_mfma_f32_16x16x32_f16(al, bh, acc[u], 0, 0, 0);
            }
        }
#pragma unroll
        for (int u = 0; u < 4; ++u)
#pragma unroll
            for (int r = 0; r < 4; ++r)
                h[u][r] = fmaxf(acc[u][r], 0.2f * acc[u][r]);
    }

    // ---- 32 residual layers, NT tiles interleaved.  Per-lane raw weights
    // Ws[l][q*4+j][col] prefetched 1 layer ahead (L1/L2-resident 32 KiB);
    // hi/lo split converted in-loop (bit-identical to the old prep table).
    // Rolled loop (unroll 1) keeps the prefetch exactly 1-deep.
    const float* wlane = Ws + (q * 4) * H + col;   // + l*256 + j*16
    float wraw[4];
#pragma unroll
    for (int j = 0; j < 4; ++j) wraw[j] = wlane[j * H];
#pragma unroll 1
    for (int l = 0; l < NLAYERS; ++l) {
        // issue next layer's 4 loads first (independent of conversion below)
        float wnext[4];
        {
            const int ln = (l + 1) & (NLAYERS - 1);  // wraps at l=31; harmless
            const float* wl = wlane + ln * H * H;
#pragma unroll
            for (int j = 0; j < 4; ++j) wnext[j] = wl[j * H];
        }
        // convert current layer: wc = {hi[0:4] | lo[0:4]}, RNE casts as before
        half8 wc;
#pragma unroll
        for (int j = 0; j < 4; ++j) {
            float w = wraw[j];
            _Float16 hi = (_Float16)w;
            wc[j] = hi;                              // slots j<4: hi (pairs hlo)
            wc[j + 4] = (_Float16)(w - (float)hi);   // slots j>=4: lo (pairs hhi)
        }
        half4 wh = low_half(wc);          // == hi(Ws^T) fragment, free extract
        floatx4 bias = lds_bs[l * 4 + q];

#pragma unroll
        for (int i = 0; i < NT; ++i) {
            // hi = f16_rtz(h); float(hi) == h & 0xFFFFE000 for normal h.
            half4 hhi = mk_half4(__builtin_amdgcn_cvt_pkrtz(h[i][0], h[i][1]),
                                 __builtin_amdgcn_cvt_pkrtz(h[i][2], h[i][3]));
            float lo[4];
#pragma unroll
            for (int r = 0; r < 4; ++r) {
                unsigned u = __builtin_bit_cast(unsigned, h[i][r]) & 0xFFFFE000u;
                lo[r] = h[i][r] - __builtin_bit_cast(float, u);
            }
            intx2 hbits = __builtin_bit_cast(intx2, hhi);
            half8 bp = mk_half8(__builtin_amdgcn_cvt_pkrtz(lo[0], lo[1]),
                                __builtin_amdgcn_cvt_pkrtz(lo[2], lo[3]),
                                __builtin_bit_cast(pk16x2, hbits.x),
                                __builtin_bit_cast(pk16x2, hbits.y));
            floatx4 d = __builtin_amdgcn_mfma_f32_16x16x16f16(wh, hhi, bias, 0, 0, 0);
            d = __builtin_amdgcn_mfma_f32_16x16x32_f16(wc, bp, d, 0, 0, 0);
#pragma unroll
            for (int r = 0; r < 4; ++r) {
                // h += leaky(d) = 0.6d + 0.4|d|
                h[i][r] = __builtin_fmaf(0.6f, d[r], h[i][r]);
                h[i][r] = __builtin_fmaf(0.4f, __builtin_fabsf(d[r]), h[i][r]);
            }
        }
#pragma unroll
        for (int j = 0; j < 4; ++j) wraw[j] = wnext[j];
    }

    // ---- Final Dense(16->1): column n spread over 4 quads ----
#pragma unroll
    for (int i = 0; i < NT; ++i) {
        float p = h[i][0] * wf4.x;
        p = __builtin_fmaf(h[i][1], wf4.y, p);
        p = __builtin_fmaf(h[i][2], wf4.z, p);
        p = __builtin_fmaf(h[i][3], wf4.w, p);
        p += __shfl_xor(p, 16, 64);
        p += __shfl_xor(p, 32, 64);
        if (q == 0) out[n0 + i * stride16] = p + bff;
    }
}

extern "C" void kernel_launch(void* const* d_in, const int* in_sizes, int n_in,
                              void* d_out, int out_size, void* d_ws, size_t ws_size,
                              hipStream_t stream) {
    const float* z  = (const float*)d_in[0];
    const float* c  = (const float*)d_in[1];
    const float* W1 = (const float*)d_in[2];
    const float* b1 = (const float*)d_in[3];
    const float* Ws = (const float*)d_in[4];
    const float* bs = (const float*)d_in[5];
    const float* Wf = (const float*)d_in[6];
    const float* bf = (const float*)d_in[7];
    const int B = in_sizes[0] / 2;  // z is (B,2)

    const int blocks = 1024;  // 1024 x 8 waves x 4 tiles x 16 = 524288 samples
    fractal_kernel<<<blocks, 512, 0, stream>>>(z, c, W1, b1, Ws, bs, Wf, bf,
                                               (float*)d_out, B);
}

// Round 6
// 119.288 us; speedup vs baseline: 1.1398x; 1.1398x over previous
//
#include <hip/hip_runtime.h>

#define NLAYERS 32
#define H 16
#define INDIM 124
#define NT 4   // batch tiles per wave

typedef __fp16 pk16x2 __attribute__((ext_vector_type(2)));   // cvt_pkrtz result
typedef _Float16 half4 __attribute__((ext_vector_type(4)));
typedef _Float16 half8 __attribute__((ext_vector_type(8)));
typedef float floatx4 __attribute__((ext_vector_type(4)));
typedef float floatx2 __attribute__((ext_vector_type(2)));
typedef int intx2 __attribute__((ext_vector_type(2)));
typedef int intx4 __attribute__((ext_vector_type(4)));

static __device__ __forceinline__ half8 mk_half8(pk16x2 a, pk16x2 b,
                                                 pk16x2 c, pk16x2 d) {
    intx4 v;
    v.x = __builtin_bit_cast(int, a);
    v.y = __builtin_bit_cast(int, b);
    v.z = __builtin_bit_cast(int, c);
    v.w = __builtin_bit_cast(int, d);
    return __builtin_bit_cast(half8, v);
}

// Split-W f16 MFMA residual MLP.  hT lives in the MFMA D-fragment
// (m=quad*4+r, n=lane&15) == the next MFMA's B-fragment layout.
//
// This round vs round 5 (81 us kernel / 136 us bench): bench-vs-dispatch
// evidence (R0 gap ~15us at VALUBusy 45%; R3-R5 gap ~55us at VALUBusy 80%,
// invariant to workgroup count) fits a sustained power/clock limit: bench
// wall time tracks ENERGY (instruction count), not latency-hidden dispatch
// time.  So: cut instructions.  The h-side precision split (hlo extract +
// lo-pack + separate hi MFMA = 12 VALU + 1 MFMA per tile-layer) is dropped;
// W stays 22-bit exact via the {Whi|Wlo} K=32 fragment, h is quantized once
// to f16 RNE and duplicated: d = (Whi+Wlo)*h16 + b in ONE MFMA
// (bp = {h16[0:4], h16[0:4]} pairs A' slots j<4=Whi[4q+j], j>=4=Wlo[4q+j]).
// Error budget: h-quant 2^-12 rel * ~2x downstream gain * 32 layers ->
// absmax ~0.1-0.25 vs 0.3625 threshold.
// leaky(x) = 0.6x + 0.4|x| -> two FMAs (|x| is a free src modifier).
// Residual tile-layer cost: 14 VALU + 1 MFMA (was 24 + 2).
// LDS = 4K (w1hi) + 2K (bias) = 6144 B; 1024 blocks x 512 thr, NT=4:
// 4 blocks/CU x 8 waves = 32 waves/CU.
__global__ __launch_bounds__(512, 4) void fractal_kernel(
    const float* __restrict__ z, const float* __restrict__ c,
    const float* __restrict__ W1, const float* __restrict__ b1,
    const float* __restrict__ Ws, const float* __restrict__ bs,
    const float* __restrict__ Wf, const float* __restrict__ bf,
    float* __restrict__ out, int B)
{
    __shared__ half8 lds_w1hi[4 * 64];       // layer-1 hi A frags
    __shared__ floatx4 lds_bs[NLAYERS * 4];  // bias frags

    const int tid = threadIdx.x;
    const int lane = tid & 63;
    const int q = lane >> 4, col = lane & 15;

    // Stage W1^T hi fragments: A[m=col][k] = W1[k][col], k = t*32 + q*8 + j.
    if (tid < 256) {
        int t = tid >> 6, sl = tid & 63;
        int sq = sl >> 4, scol = sl & 15;
        half8 vh;
#pragma unroll
        for (int j = 0; j < 8; ++j) {
            int k = t * 32 + sq * 8 + j;
            float w = (k < INDIM) ? W1[k * H + scol] : 0.f;
            vh[j] = (_Float16)w;
        }
        lds_w1hi[tid] = vh;
    }
    for (int idx = tid; idx < NLAYERS * 4; idx += 512) {
        int l = idx >> 2, sq = idx & 3;
        floatx4 v;
#pragma unroll
        for (int j = 0; j < 4; ++j) v[j] = bs[l * H + sq * 4 + j];
        lds_bs[idx] = v;
    }

    // Layer-1 LO fragments live in registers (own lane's fragment only).
    half8 w1lo[4];
#pragma unroll
    for (int t = 0; t < 4; ++t) {
#pragma unroll
        for (int j = 0; j < 8; ++j) {
            int k = t * 32 + q * 8 + j;
            float w = (k < INDIM) ? W1[k * H + col] : 0.f;
            _Float16 hi = (_Float16)w;
            w1lo[t][j] = (_Float16)(w - (float)hi);
        }
    }
    __syncthreads();

    const int wave = (blockIdx.x * 512 + tid) >> 6;
    const int nwaves = (gridDim.x * 512) >> 6;   // 8192
    const int stride16 = nwaves * 16;            // batch stride between tiles

    constexpr float C_HI = 0.15915494309189535f;                        // fl(1/2pi)
    constexpr float C_LO = (float)(0.15915494309189535 - (double)C_HI); // residual

    const floatx2* z2 = (const floatx2*)z;
    const floatx2* c2 = (const floatx2*)c;
    const floatx4 bias1 = *(const floatx4*)(b1 + q * 4);
    const floatx4 wf4 = *(const floatx4*)(Wf + q * 4);
    const float bff = bf[0];

    const int n0 = wave * 16 + col;
    float h[NT][4];   // h[i][r]: master fp32 hidden state for tile i

    // ---- Layer 1: positional encoding + Dense(124->16) ----
    {
        float yh[4][4], yl[4][4];   // [tile][dim]
#pragma unroll
        for (int u = 0; u < 4; ++u) {
            const int n = n0 + u * stride16;
            floatx2 zz = z2[n], cc = c2[n];
            float xv[4] = {zz.x, zz.y, cc.x, cc.y};
            // two-float x/(2pi): x*2^i exact in fp32, so frac((yh+yl)*2^i)
            // gives an accurate phase for sin(x*2^i) without Payne-Hanek.
#pragma unroll
            for (int d = 0; d < 4; ++d) {
                yh[u][d] = xv[d] * C_HI;
                yl[u][d] = __builtin_fmaf(xv[d], C_HI, -yh[u][d]) + xv[d] * C_LO;
            }
            // raw features x_d needed later (t=0 cos slots, q==0); stash in h[].
#pragma unroll
            for (int r = 0; r < 4; ++r) h[u][r] = xv[r];
        }
        floatx4 acc[4] = {bias1, bias1, bias1, bias1};
#pragma unroll
        for (int t = 0; t < 4; ++t) {
            // features k = t*32 + q*8 + j: j<4 -> cos(2^(t*4+q-1) x_d),
            // j>=4 -> sin(2^(t*4+q) x_d), d=j&3; t=0,q=0,j<4 -> raw x.
            // k=124..127 hit zeroed A columns — values harmless.
            const float sc_cos = __builtin_ldexpf(1.0f, t * 4 + q - 1);
            const float sc_sin = __builtin_ldexpf(1.0f, t * 4 + q);
            half8 ah = lds_w1hi[t * 64 + lane];   // shared across 4 tiles
            half8 al = w1lo[t];
#pragma unroll
            for (int u = 0; u < 4; ++u) {
                float fv[8];
#pragma unroll
                for (int j = 0; j < 8; ++j) {
                    const int d = j & 3;
                    const bool is_cos = (j < 4);
                    const float sc = is_cos ? sc_cos : sc_sin;
                    float fr = __builtin_amdgcn_fractf(yh[u][d] * sc);
                    fr = __builtin_fmaf(yl[u][d], sc, fr);
                    if (is_cos) fr += 0.25f;             // cos = sin(+1/4 rev)
                    fv[j] = __builtin_amdgcn_sinf(fr);
                    if (t == 0 && is_cos && q == 0) fv[j] = h[u][j];
                }
                half8 bh = mk_half8(__builtin_amdgcn_cvt_pkrtz(fv[0], fv[1]),
                                    __builtin_amdgcn_cvt_pkrtz(fv[2], fv[3]),
                                    __builtin_amdgcn_cvt_pkrtz(fv[4], fv[5]),
                                    __builtin_amdgcn_cvt_pkrtz(fv[6], fv[7]));
                acc[u] = __builtin_amdgcn_mfma_f32_16x16x32_f16(ah, bh, acc[u], 0, 0, 0);
                acc[u] = __builtin_amdgcn_mfma_f32_16x16x32_f16(al, bh, acc[u], 0, 0, 0);
            }
        }
#pragma unroll
        for (int u = 0; u < 4; ++u)
#pragma unroll
            for (int r = 0; r < 4; ++r)
                h[u][r] = fmaxf(acc[u][r], 0.2f * acc[u][r]);
    }

    // ---- 32 residual layers, NT tiles interleaved.  Per-lane raw weights
    // Ws[l][q*4+j][col] prefetched 1 layer ahead (L1/L2-resident 32 KiB);
    // {hi|lo} split converted in-loop.  Rolled loop (unroll 1) keeps the
    // prefetch exactly 1-deep.
    const float* wlane = Ws + (q * 4) * H + col;   // + l*256 + j*16
    float wraw[4];
#pragma unroll
    for (int j = 0; j < 4; ++j) wraw[j] = wlane[j * H];
#pragma unroll 1
    for (int l = 0; l < NLAYERS; ++l) {
        // issue next layer's 4 loads first (independent of conversion below)
        float wnext[4];
        {
            const int ln = (l + 1) & (NLAYERS - 1);  // wraps at l=31; harmless
            const float* wl = wlane + ln * H * H;
#pragma unroll
            for (int j = 0; j < 4; ++j) wnext[j] = wl[j * H];
        }
        // convert current layer: wc = {hi[0:4] | lo[0:4]}, RNE casts
        half8 wc;
#pragma unroll
        for (int j = 0; j < 4; ++j) {
            float w = wraw[j];
            _Float16 hi = (_Float16)w;
            wc[j] = hi;                              // slots j<4: hi
            wc[j + 4] = (_Float16)(w - (float)hi);   // slots j>=4: lo
        }
        floatx4 bias = lds_bs[l * 4 + q];

#pragma unroll
        for (int i = 0; i < NT; ++i) {
            // h16 = f16_rne(h); single K=32 MFMA computes (Whi+Wlo)*h16 + b:
            // bp slot j<4 pairs Whi[4q+j], slot j>=4 pairs Wlo[4q+j-4],
            // both multiply the lane's own h16[0..3] -> duplicate words.
            half4 h4;
#pragma unroll
            for (int r = 0; r < 4; ++r) h4[r] = (_Float16)h[i][r];
            intx2 hb = __builtin_bit_cast(intx2, h4);
            intx4 bv; bv.x = hb.x; bv.y = hb.y; bv.z = hb.x; bv.w = hb.y;
            half8 bp = __builtin_bit_cast(half8, bv);
            floatx4 d = __builtin_amdgcn_mfma_f32_16x16x32_f16(wc, bp, bias, 0, 0, 0);
#pragma unroll
            for (int r = 0; r < 4; ++r) {
                // h += leaky(d) = 0.6d + 0.4|d|
                h[i][r] = __builtin_fmaf(0.6f, d[r], h[i][r]);
                h[i][r] = __builtin_fmaf(0.4f, __builtin_fabsf(d[r]), h[i][r]);
            }
        }
#pragma unroll
        for (int j = 0; j < 4; ++j) wraw[j] = wnext[j];
    }

    // ---- Final Dense(16->1): column n spread over 4 quads ----
#pragma unroll
    for (int i = 0; i < NT; ++i) {
        float p = h[i][0] * wf4.x;
        p = __builtin_fmaf(h[i][1], wf4.y, p);
        p = __builtin_fmaf(h[i][2], wf4.z, p);
        p = __builtin_fmaf(h[i][3], wf4.w, p);
        p += __shfl_xor(p, 16, 64);
        p += __shfl_xor(p, 32, 64);
        if (q == 0) out[n0 + i * stride16] = p + bff;
    }
}

extern "C" void kernel_launch(void* const* d_in, const int* in_sizes, int n_in,
                              void* d_out, int out_size, void* d_ws, size_t ws_size,
                              hipStream_t stream) {
    const float* z  = (const float*)d_in[0];
    const float* c  = (const float*)d_in[1];
    const float* W1 = (const float*)d_in[2];
    const float* b1 = (const float*)d_in[3];
    const float* Ws = (const float*)d_in[4];
    const float* bs = (const float*)d_in[5];
    const float* Wf = (const float*)d_in[6];
    const float* bf = (const float*)d_in[7];
    const int B = in_sizes[0] / 2;  // z is (B,2)

    const int blocks = 1024;  // 1024 x 8 waves x 4 tiles x 16 = 524288 samples
    fractal_kernel<<<blocks, 512, 0, stream>>>(z, c, W1, b1, Ws, bs, Wf, bf,
                                               (float*)d_out, B);
}